// Round 14
// baseline (137.299 us; speedup 1.0000x reference)
//
#include <hip/hip_runtime.h>
#include <cstddef>

#define CC 256
#define HH 128
#define WW 128
#define HW (HH*WW)          // 16384

typedef __attribute__((ext_vector_type(8))) short short8v;   // 8 bf16
typedef __attribute__((ext_vector_type(4))) float float4v;   // MFMA acc

__device__ __forceinline__ short f2bf(float x) {
    unsigned u = __float_as_uint(x);
    u += 0x7FFFu + ((u >> 16) & 1u);      // RNE to bf16
    return (short)(u >> 16);
}
__device__ __forceinline__ float4 add4(float4 a, float4 b) {
    float4 r; r.x=a.x+b.x; r.y=a.y+b.y; r.z=a.z+b.z; r.w=a.w+b.w; return r;
}
__device__ __forceinline__ float4 scale4(float4 a, float s) {
    float4 r; r.x=a.x*s; r.y=a.y*s; r.z=a.z*s; r.w=a.w*s; return r;
}
__device__ __forceinline__ float4 shflx4(float4 v, int m) {
    float4 r;
    r.x = __shfl_xor(v.x, m); r.y = __shfl_xor(v.y, m);
    r.z = __shfl_xor(v.z, m); r.w = __shfl_xor(v.w, m);
    return r;
}
__device__ __forceinline__ float hsum4(float4 v) { return v.x+v.y+v.z+v.w; }

// ============ Kernel 1: fused pooling + both energies (DS-pipe-lean) ============
// grid 1024: b = bid&7, chunk = bid>>3 (2 c's per block). block 512 (8 waves).
// Shuffle-free pooling: H-pool via in-lane 8-row sums (R1 ownership);
// W-pools via row-ownership second pass (L1/L2-hot) writing coalesced u16.
__global__ __launch_bounds__(512) void fused_pool_energy(
    const float* __restrict__ t1, const float* __restrict__ t2,
    unsigned short* __restrict__ valHT, unsigned short* __restrict__ valWbf,
    float* __restrict__ PH, float* __restrict__ PW)
{
    __shared__ __align__(16) short t2lds[64*128];   // [h_local][w]   swz (h&7)<<3   16KB
    __shared__ __align__(16) short t2T  [128*64];   // [w][h_local]   swz ((w>>1)&7)<<3  16KB
    __shared__ __align__(16) short kH   [16*128];   // [k][w]         swz (k&7)<<3    4KB
    __shared__ __align__(16) short kWT  [16*128];   // [k][h_global]  swz (k&7)<<3    4KB

    const int bid   = blockIdx.x;
    const int b     = bid & 7;
    const int chunk = bid >> 3;            // 0..127
    const int c0    = chunk * 2;
    const int tid   = threadIdx.x;
    const int l     = tid & 63;
    const int v     = tid >> 6;            // wave 0..7
    const int w4    = l & 31;              // float4 column
    const int rq    = l >> 5;              // row quad within wave's 8 rows

    float4v accH = {0.f,0.f,0.f,0.f};      // wave v: H-tile v  (D[h][k])
    float4v accW = {0.f,0.f,0.f,0.f};      // wave v: W-tile v  (D[k][w])

    for (int ci = 0; ci < 2; ++ci) {
        const int c = c0 + ci;
        const int bc = b*CC + c;
        const size_t cbase = (size_t)bc * HW;
        const float4* t1c = (const float4*)(t1 + cbase);
        const float4* t2c = (const float4*)(t2 + cbase);

        // ---------- t1 pass: keys (shuffle-free) ----------
        // H-pool: thread owns k = tid>>5 (8 rows), f4-col q — in-lane sum.
        {
            const int k = tid >> 5;        // 0..15
            const int q = tid & 31;
            const float4* p = t1c + k*256 + q;
            float4 s = {0.f,0.f,0.f,0.f};
            #pragma unroll
            for (int j = 0; j < 8; ++j) s = add4(s, p[j*32]);
            float4 m4 = scale4(s, 0.125f);
            short4 pk; pk.x=f2bf(m4.x); pk.y=f2bf(m4.y); pk.z=f2bf(m4.z); pk.w=f2bf(m4.w);
            *(short4*)&kH[k*128 + ((q*4) ^ ((k&7)<<3))] = pk;
        }
        // W-pool: lane owns (row, kw) — 2 contiguous f4 reads (cache-hot), 1 u16 write.
        #pragma unroll
        for (int it = 0; it < 4; ++it) {
            const int r  = it*32 + v*4 + (l>>4);   // 0..127
            const int kw = l & 15;
            const float4* p = t1c + r*32 + kw*2;
            float s = (hsum4(p[0]) + hsum4(p[1])) * 0.125f;
            kWT[kw*128 + (r ^ ((kw&7)<<3))] = f2bf(s);
        }
        __syncthreads();

        // ---------- t2 halves: stage + MFMA ----------
        #pragma unroll
        for (int half = 0; half < 2; ++half) {
            const int hbase = half*64 + v*8 + rq*4;   // global h of first row
            const int hl4   = v*8 + rq*4;             // local h (0..63)
            const float4* src = t2c + hbase*32 + w4;
            float4 x0 = src[0], x1 = src[32], x2 = src[64], x3 = src[96];

            // pool-H -> valHT bf16 [w][16] (one shfl pair; global scatter rq==0)
            float4 s4 = add4(add4(x0,x1), add4(x2,x3));
            float4 m4 = scale4(add4(s4, shflx4(s4,32)), 0.125f);
            if (rq == 0) {
                const int k = half*8 + v;
                const size_t vb = (size_t)bc * 2048;
                valHT[vb + (w4*4+0)*16 + k] = (unsigned short)f2bf(m4.x);
                valHT[vb + (w4*4+1)*16 + k] = (unsigned short)f2bf(m4.y);
                valHT[vb + (w4*4+2)*16 + k] = (unsigned short)f2bf(m4.z);
                valHT[vb + (w4*4+3)*16 + k] = (unsigned short)f2bf(m4.w);
            }
            // pool-W -> valWbf bf16 [h][16]: row-ownership, cache-hot, coalesced u16
            #pragma unroll
            for (int it = 0; it < 2; ++it) {
                const int rl = it*32 + v*4 + (l>>4);      // 0..63 local
                const int kw = l & 15;
                const float4* p = t2c + (half*64 + rl)*32 + kw*2;
                float s = (hsum4(p[0]) + hsum4(p[1])) * 0.125f;
                valWbf[(size_t)bc*2048 + (size_t)(half*64 + rl)*16 + kw] = f2bf(s);
            }
            // bf16 convert + LDS stage (row-major and transposed)
            short s0x=f2bf(x0.x), s0y=f2bf(x0.y), s0z=f2bf(x0.z), s0w=f2bf(x0.w);
            short s1x=f2bf(x1.x), s1y=f2bf(x1.y), s1z=f2bf(x1.z), s1w=f2bf(x1.w);
            short s2x=f2bf(x2.x), s2y=f2bf(x2.y), s2z=f2bf(x2.z), s2w=f2bf(x2.w);
            short s3x=f2bf(x3.x), s3y=f2bf(x3.y), s3z=f2bf(x3.z), s3w=f2bf(x3.w);
            {
                short4 p;
                p.x=s0x; p.y=s0y; p.z=s0z; p.w=s0w;
                *(short4*)&t2lds[(hl4+0)*128 + ((w4*4) ^ (((hl4+0)&7)<<3))] = p;
                p.x=s1x; p.y=s1y; p.z=s1z; p.w=s1w;
                *(short4*)&t2lds[(hl4+1)*128 + ((w4*4) ^ (((hl4+1)&7)<<3))] = p;
                p.x=s2x; p.y=s2y; p.z=s2z; p.w=s2w;
                *(short4*)&t2lds[(hl4+2)*128 + ((w4*4) ^ (((hl4+2)&7)<<3))] = p;
                p.x=s3x; p.y=s3y; p.z=s3z; p.w=s3w;
                *(short4*)&t2lds[(hl4+3)*128 + ((w4*4) ^ (((hl4+3)&7)<<3))] = p;
            }
            {   // in-register 4x4 transpose -> t2T columns
                short4 p;
                int w = w4*4 + 0;
                p.x=s0x; p.y=s1x; p.z=s2x; p.w=s3x;
                *(short4*)&t2T[w*64 + (hl4 ^ (((w>>1)&7)<<3))] = p;
                w = w4*4 + 1;
                p.x=s0y; p.y=s1y; p.z=s2y; p.w=s3y;
                *(short4*)&t2T[w*64 + (hl4 ^ (((w>>1)&7)<<3))] = p;
                w = w4*4 + 2;
                p.x=s0z; p.y=s1z; p.z=s2z; p.w=s3z;
                *(short4*)&t2T[w*64 + (hl4 ^ (((w>>1)&7)<<3))] = p;
                w = w4*4 + 3;
                p.x=s0w; p.y=s1w; p.z=s2w; p.w=s3w;
                *(short4*)&t2T[w*64 + (hl4 ^ (((w>>1)&7)<<3))] = p;
            }
            __syncthreads();

            // ---- MFMA: H branch (waves whose h-tile lives in this half) ----
            if ((v >> 2) == half) {
                const int hl = (v & 3)*16 + (l & 15);
                const int kb = l & 15;
                #pragma unroll
                for (int ws2 = 0; ws2 < 4; ++ws2) {
                    const int wb = ws2*32 + (l>>4)*8;
                    short8v A  = *(const short8v*)&t2lds[hl*128 + (wb ^ ((hl&7)<<3))];
                    short8v B  = *(const short8v*)&kH  [kb*128 + (wb ^ ((kb&7)<<3))];
                    accH = __builtin_amdgcn_mfma_f32_16x16x32_bf16(A, B, accH, 0, 0, 0);
                }
            }
            // ---- MFMA: W branch (all waves; wave v owns w-tile v) ----
            {
                const int kb = l & 15;
                const int w  = v*16 + (l & 15);
                #pragma unroll
                for (int hs = 0; hs < 2; ++hs) {
                    const int hloc = hs*32 + (l>>4)*8;
                    const int hg   = half*64 + hloc;
                    short8v A = *(const short8v*)&kWT[kb*128 + (hg  ^ ((kb&7)<<3))];
                    short8v B = *(const short8v*)&t2T[w*64   + (hloc ^ (((w>>1)&7)<<3))];
                    accW = __builtin_amdgcn_mfma_f32_16x16x32_bf16(A, B, accW, 0, 0, 0);
                }
            }
            __syncthreads();
        }
    }

    // ---------- write partials ----------
    {
        const size_t pb = ((size_t)(b*128 + chunk)) * 2048;
        #pragma unroll
        for (int r = 0; r < 4; ++r) {
            const int h = v*16 + (l>>4)*4 + r;
            PH[pb + h*16 + (l&15)] = accH[r];
            const int k = (l>>4)*4 + r;
            PW[pb + k*128 + v*16 + (l&15)] = accW[r];
        }
    }
}

// ============ Kernel 2: reduce partials (128 chunk-records) -> energy[8][4096] ====
__global__ __launch_bounds__(256) void energy_reduce(
    const float* __restrict__ PH, const float* __restrict__ PW,
    float* __restrict__ energy, float* __restrict__ bmin, float* __restrict__ bmax)
{
    const int bidx = blockIdx.x;           // 0..511
    const int tid  = threadIdx.x;
    const int ol   = tid & 63, qd = tid >> 6;
    const int o    = bidx*64 + ol;         // 0..32767
    __shared__ float red[4][64];

    const int isW = o >> 14;
    const int oo  = o & 16383;
    const int b   = oo >> 11, i = oo & 2047;
    const float* P = (isW ? PW : PH) + (size_t)b*128*2048 + i;
    float s = 0.f;
    #pragma unroll
    for (int j = 0; j < 32; ++j) s += P[(size_t)(qd*32 + j)*2048];
    red[qd][ol] = s;
    __syncthreads();

    if (tid < 64) {
        float v = red[0][tid] + red[1][tid] + red[2][tid] + red[3][tid];
        const int o2 = bidx*64 + tid;
        const int oo2 = o2 & 16383;
        const int b2 = oo2 >> 11, i2 = oo2 & 2047;
        const size_t dst = (o2 >> 14)
            ? ((size_t)b2*4096 + 2048 + (size_t)(i2 & 127)*16 + (i2 >> 7))
            : ((size_t)b2*4096 + i2);
        energy[dst] = v;
        float mn = v, mx = v;
        #pragma unroll
        for (int sft = 32; sft > 0; sft >>= 1) {
            mn = fminf(mn, __shfl_xor(mn, sft));
            mx = fmaxf(mx, __shfl_xor(mx, sft));
        }
        if (tid == 0) { bmin[bidx] = mn; bmax[bidx] = mx; }
    }
}

// ============ Kernel 3: recombination, softmax computed inline ============
// grid 2048 (b = bid&7, c = bid>>3), block 256 (4 waves).
__global__ __launch_bounds__(256) void out_kernel(
    const float* __restrict__ t2,
    const unsigned short* __restrict__ valHT,   // [b][c][w][16]
    const unsigned short* __restrict__ valWbf,  // [b][c][h][16]
    const float* __restrict__ energy,           // [b][4096]
    const float* __restrict__ bmin, const float* __restrict__ bmax,
    float* __restrict__ out)
{
    __shared__ __align__(16) unsigned short attbf[4096];  // [h][16] | [w][16]  8KB
    __shared__ float rmn[4], rmx[4], rsum[4], bc2[2];

    const int bid = blockIdx.x;
    const int b = bid & 7, c = bid >> 3;
    const int bc = b*CC + c;
    const int tid = threadIdx.x;
    const int l  = tid & 63;
    const int wv = tid >> 6;       // 0..3
    const int ln = l & 15;
    const int q4 = l >> 4;         // k-quadrant
    const size_t tb = (size_t)bc * HW;

    // ---- global min/max from bmin/bmax[512] ----
    {
        float mn = fminf(bmin[tid], bmin[tid + 256]);
        float mx = fmaxf(bmax[tid], bmax[tid + 256]);
        #pragma unroll
        for (int s = 32; s > 0; s >>= 1) {
            mn = fminf(mn, __shfl_xor(mn, s));
            mx = fmaxf(mx, __shfl_xor(mx, s));
        }
        if (l == 0) { rmn[wv] = mn; rmx[wv] = mx; }
    }
    __syncthreads();
    if (tid == 0) {
        float a = fminf(fminf(rmn[0], rmn[1]), fminf(rmn[2], rmn[3]));
        float m = fmaxf(fmaxf(rmx[0], rmx[1]), fmaxf(rmx[2], rmx[3]));
        bc2[0] = a; bc2[1] = 1.0f / (m - a);
    }
    __syncthreads();
    const float gmn = bc2[0];
    const float inv = bc2[1];

    // ---- softmax over the full 4096 (thread owns 16 contiguous values) ----
    float ex[16];
    {
        const float4* ep = (const float4*)(energy + (size_t)b*4096 + tid*16);
        float4 e0 = ep[0], e1 = ep[1], e2 = ep[2], e3 = ep[3];
        ex[0]=__expf((e0.x-gmn)*inv); ex[1]=__expf((e0.y-gmn)*inv);
        ex[2]=__expf((e0.z-gmn)*inv); ex[3]=__expf((e0.w-gmn)*inv);
        ex[4]=__expf((e1.x-gmn)*inv); ex[5]=__expf((e1.y-gmn)*inv);
        ex[6]=__expf((e1.z-gmn)*inv); ex[7]=__expf((e1.w-gmn)*inv);
        ex[8]=__expf((e2.x-gmn)*inv); ex[9]=__expf((e2.y-gmn)*inv);
        ex[10]=__expf((e2.z-gmn)*inv); ex[11]=__expf((e2.w-gmn)*inv);
        ex[12]=__expf((e3.x-gmn)*inv); ex[13]=__expf((e3.y-gmn)*inv);
        ex[14]=__expf((e3.z-gmn)*inv); ex[15]=__expf((e3.w-gmn)*inv);
        float ls = 0.f;
        #pragma unroll
        for (int i = 0; i < 16; ++i) ls += ex[i];
        #pragma unroll
        for (int s = 32; s > 0; s >>= 1) ls += __shfl_xor(ls, s);
        if (l == 0) rsum[wv] = ls;
    }
    __syncthreads();
    if (tid == 0) bc2[0] = 1.0f / (rsum[0] + rsum[1] + rsum[2] + rsum[3]);
    __syncthreads();
    {
        const float rinv = bc2[0];
        short8v o0, o1;
        #pragma unroll
        for (int i = 0; i < 8; ++i) o0[i] = f2bf(ex[i] * rinv);
        #pragma unroll
        for (int i = 0; i < 8; ++i) o1[i] = f2bf(ex[8 + i] * rinv);
        *(short8v*)&attbf[tid*16]     = o0;
        *(short8v*)&attbf[tid*16 + 8] = o1;
    }
    __syncthreads();

    // ---- MFMA epilogue (att from LDS; vals from global) ----
    const unsigned short* vHT = valHT  + (size_t)bc*2048;   // [w][16]
    const unsigned short* vW  = valWbf + (size_t)bc*2048;   // [h][16]

    short8v Bf[8];
    #pragma unroll
    for (int tw = 0; tw < 8; ++tw) {
        if (q4 < 2)
            Bf[tw] = *(const short8v*)&vHT[(tw*16 + ln)*16 + (q4 & 1)*8];
        else
            Bf[tw] = *(const short8v*)&attbf[2048 + (tw*16 + ln)*16 + (q4 & 1)*8];
    }

    #pragma unroll
    for (int t = 0; t < 2; ++t) {
        const int th = wv*2 + t;
        short8v Af;
        if (q4 < 2)
            Af = *(const short8v*)&attbf[(th*16 + ln)*16 + (q4 & 1)*8];
        else
            Af = *(const short8v*)&vW[(th*16 + ln)*16 + (q4 & 1)*8];
        #pragma unroll
        for (int tw = 0; tw < 8; ++tw) {
            float4v acc = {0.f,0.f,0.f,0.f};
            acc = __builtin_amdgcn_mfma_f32_16x16x32_bf16(Af, Bf[tw], acc, 0, 0, 0);
            const size_t base = tb + (size_t)(th*16 + q4*4)*128 + tw*16 + ln;
            #pragma unroll
            for (int r = 0; r < 4; ++r) {
                const float tv = t2[base + (size_t)r*128];
                out[base + (size_t)r*128] = fmaf(0.5f, acc[r], tv);
            }
        }
    }
}

extern "C" void kernel_launch(void* const* d_in, const int* in_sizes, int n_in,
                              void* d_out, int out_size, void* d_ws, size_t ws_size,
                              hipStream_t stream)
{
    const float* t1 = (const float*)d_in[0];
    const float* t2 = (const float*)d_in[1];
    float* out = (float*)d_out;
    char*  ws  = (char*)d_ws;

    unsigned short* valHT  = (unsigned short*)ws;                       // 8 MB
    unsigned short* valWbf = (unsigned short*)(ws + ((size_t)8 << 20)); // 8 MB
    float* energy = (float*)(ws + ((size_t)16 << 20));                  // 128 KB
    float* bmin   = energy + 32768;
    float* bmax   = bmin + 512;

    // partials live in d_out (16 MB of 134 MB), overwritten by out_kernel
    float* PH = out;                        // 1024*2048 floats = 8 MB
    float* PW = out + (size_t)2097152;      // 8 MB

    hipLaunchKernelGGL(fused_pool_energy, dim3(1024), dim3(512), 0, stream,
                       t1, t2, valHT, valWbf, PH, PW);
    hipLaunchKernelGGL(energy_reduce, dim3(512), dim3(256), 0, stream,
                       PH, PW, energy, bmin, bmax);
    hipLaunchKernelGGL(out_kernel, dim3(2048), dim3(256), 0, stream,
                       t2, valHT, valWbf, energy, bmin, bmax, out);
}

// Round 15
// 122.983 us; speedup vs baseline: 1.1164x; 1.1164x over previous
//
#include <hip/hip_runtime.h>
#include <cstddef>

#define CC 256
#define HH 128
#define WW 128
#define HW (HH*WW)          // 16384

typedef __attribute__((ext_vector_type(8))) short short8v;   // 8 bf16
typedef __attribute__((ext_vector_type(4))) float float4v;   // MFMA acc

__device__ __forceinline__ short f2bf(float x) {
    unsigned u = __float_as_uint(x);
    u += 0x7FFFu + ((u >> 16) & 1u);      // RNE to bf16
    return (short)(u >> 16);
}
__device__ __forceinline__ float4 add4(float4 a, float4 b) {
    float4 r; r.x=a.x+b.x; r.y=a.y+b.y; r.z=a.z+b.z; r.w=a.w+b.w; return r;
}
__device__ __forceinline__ float4 scale4(float4 a, float s) {
    float4 r; r.x=a.x*s; r.y=a.y*s; r.z=a.z*s; r.w=a.w*s; return r;
}
__device__ __forceinline__ float4 shflx4(float4 v, int m) {
    float4 r;
    r.x = __shfl_xor(v.x, m); r.y = __shfl_xor(v.y, m);
    r.z = __shfl_xor(v.z, m); r.w = __shfl_xor(v.w, m);
    return r;
}
__device__ __forceinline__ float hsum4(float4 v) { return v.x+v.y+v.z+v.w; }

// ============ Kernel 1: fused pooling + both energies (R13 body, 4 c's) ============
// grid 512: b = bid&7, grp = bid>>3 (4 c's per block). block 512 (8 waves).
__global__ __launch_bounds__(512) void fused_pool_energy(
    const float* __restrict__ t1, const float* __restrict__ t2,
    unsigned short* __restrict__ valHT, unsigned short* __restrict__ valWbf,
    float* __restrict__ PH, float* __restrict__ PW)
{
    __shared__ __align__(16) short t2lds[64*128];   // [h_local][w]   swz (h&7)<<3   16KB
    __shared__ __align__(16) short t2T  [128*64];   // [w][h_local]   swz ((w>>1)&7)<<3  16KB
    __shared__ __align__(16) short kH   [16*128];   // [k][w]         swz (k&7)<<3    4KB
    __shared__ __align__(16) short kWT  [16*128];   // [k][h_global]  swz (k&7)<<3    4KB

    const int bid = blockIdx.x;
    const int b   = bid & 7;
    const int grp = bid >> 3;              // 0..63
    const int c0  = grp * 4;
    const int tid = threadIdx.x;
    const int l   = tid & 63;
    const int v   = tid >> 6;              // wave 0..7
    const int w4  = l & 31;                // float4 column
    const int rq  = l >> 5;                // row quad within wave's 8 rows

    float4v accH = {0.f,0.f,0.f,0.f};      // wave v: H-tile v  (D[h][k])
    float4v accW = {0.f,0.f,0.f,0.f};      // wave v: W-tile v  (D[k][w])

    for (int ci = 0; ci < 4; ++ci) {
        const int c = c0 + ci;
        const int bc = b*CC + c;
        const size_t cbase = (size_t)bc * HW;

        // ---------- t1 pass: pool keys into LDS ----------
        #pragma unroll
        for (int half = 0; half < 2; ++half) {
            const int hbase = half*64 + v*8 + rq*4;
            const float4* src = (const float4*)(t1 + cbase + (size_t)hbase * WW) + w4;
            float4 x0 = src[0], x1 = src[32], x2 = src[64], x3 = src[96];
            float4 s4 = add4(add4(x0,x1), add4(x2,x3));
            float4 m4 = scale4(add4(s4, shflx4(s4,32)), 0.125f);
            if (rq == 0) {
                const int k = half*8 + v;
                short4 p; p.x=f2bf(m4.x); p.y=f2bf(m4.y); p.z=f2bf(m4.z); p.w=f2bf(m4.w);
                *(short4*)&kH[k*128 + ((w4*4) ^ ((k&7)<<3))] = p;
            }
            float rs0 = hsum4(x0), rs1 = hsum4(x1), rs2 = hsum4(x2), rs3 = hsum4(x3);
            float o0 = __shfl_xor(rs0,1), o1 = __shfl_xor(rs1,1);
            float o2 = __shfl_xor(rs2,1), o3 = __shfl_xor(rs3,1);
            if ((l & 1) == 0) {
                const int kw = w4 >> 1;
                const int sw = (kw & 7) << 3;
                kWT[kw*128 + ((hbase+0) ^ sw)] = f2bf((rs0+o0)*0.125f);
                kWT[kw*128 + ((hbase+1) ^ sw)] = f2bf((rs1+o1)*0.125f);
                kWT[kw*128 + ((hbase+2) ^ sw)] = f2bf((rs2+o2)*0.125f);
                kWT[kw*128 + ((hbase+3) ^ sw)] = f2bf((rs3+o3)*0.125f);
            }
        }
        __syncthreads();

        // ---------- t2 halves: stage + MFMA ----------
        #pragma unroll
        for (int half = 0; half < 2; ++half) {
            const int hbase = half*64 + v*8 + rq*4;   // global h of first row
            const int hl4   = v*8 + rq*4;             // local h (0..63)
            const float4* src = (const float4*)(t2 + cbase + (size_t)hbase * WW) + w4;
            float4 x0 = src[0], x1 = src[32], x2 = src[64], x3 = src[96];

            // pool-H -> valHT bf16 [w][16] (global scatter, lanes rq==0)
            float4 s4 = add4(add4(x0,x1), add4(x2,x3));
            float4 m4 = scale4(add4(s4, shflx4(s4,32)), 0.125f);
            if (rq == 0) {
                const int k = half*8 + v;
                const size_t vb = (size_t)bc * 2048;
                valHT[vb + (w4*4+0)*16 + k] = (unsigned short)f2bf(m4.x);
                valHT[vb + (w4*4+1)*16 + k] = (unsigned short)f2bf(m4.y);
                valHT[vb + (w4*4+2)*16 + k] = (unsigned short)f2bf(m4.z);
                valHT[vb + (w4*4+3)*16 + k] = (unsigned short)f2bf(m4.w);
            }
            // pool-W -> valWbf bf16 [h][16] (global scatter, even lanes)
            {
                float rs0 = hsum4(x0), rs1 = hsum4(x1), rs2 = hsum4(x2), rs3 = hsum4(x3);
                float o0 = __shfl_xor(rs0,1), o1 = __shfl_xor(rs1,1);
                float o2 = __shfl_xor(rs2,1), o3 = __shfl_xor(rs3,1);
                if ((l & 1) == 0) {
                    const int kw = w4 >> 1;
                    const size_t vb = (size_t)bc*2048 + (size_t)hbase*16 + kw;
                    valWbf[vb +  0] = (unsigned short)f2bf((rs0+o0)*0.125f);
                    valWbf[vb + 16] = (unsigned short)f2bf((rs1+o1)*0.125f);
                    valWbf[vb + 32] = (unsigned short)f2bf((rs2+o2)*0.125f);
                    valWbf[vb + 48] = (unsigned short)f2bf((rs3+o3)*0.125f);
                }
            }
            // bf16 convert + LDS stage (row-major and transposed)
            short s0x=f2bf(x0.x), s0y=f2bf(x0.y), s0z=f2bf(x0.z), s0w=f2bf(x0.w);
            short s1x=f2bf(x1.x), s1y=f2bf(x1.y), s1z=f2bf(x1.z), s1w=f2bf(x1.w);
            short s2x=f2bf(x2.x), s2y=f2bf(x2.y), s2z=f2bf(x2.z), s2w=f2bf(x2.w);
            short s3x=f2bf(x3.x), s3y=f2bf(x3.y), s3z=f2bf(x3.z), s3w=f2bf(x3.w);
            {
                short4 p;
                p.x=s0x; p.y=s0y; p.z=s0z; p.w=s0w;
                *(short4*)&t2lds[(hl4+0)*128 + ((w4*4) ^ (((hl4+0)&7)<<3))] = p;
                p.x=s1x; p.y=s1y; p.z=s1z; p.w=s1w;
                *(short4*)&t2lds[(hl4+1)*128 + ((w4*4) ^ (((hl4+1)&7)<<3))] = p;
                p.x=s2x; p.y=s2y; p.z=s2z; p.w=s2w;
                *(short4*)&t2lds[(hl4+2)*128 + ((w4*4) ^ (((hl4+2)&7)<<3))] = p;
                p.x=s3x; p.y=s3y; p.z=s3z; p.w=s3w;
                *(short4*)&t2lds[(hl4+3)*128 + ((w4*4) ^ (((hl4+3)&7)<<3))] = p;
            }
            {   // in-register 4x4 transpose -> t2T columns
                short4 p;
                int w = w4*4 + 0;
                p.x=s0x; p.y=s1x; p.z=s2x; p.w=s3x;
                *(short4*)&t2T[w*64 + (hl4 ^ (((w>>1)&7)<<3))] = p;
                w = w4*4 + 1;
                p.x=s0y; p.y=s1y; p.z=s2y; p.w=s3y;
                *(short4*)&t2T[w*64 + (hl4 ^ (((w>>1)&7)<<3))] = p;
                w = w4*4 + 2;
                p.x=s0z; p.y=s1z; p.z=s2z; p.w=s3z;
                *(short4*)&t2T[w*64 + (hl4 ^ (((w>>1)&7)<<3))] = p;
                w = w4*4 + 3;
                p.x=s0w; p.y=s1w; p.z=s2w; p.w=s3w;
                *(short4*)&t2T[w*64 + (hl4 ^ (((w>>1)&7)<<3))] = p;
            }
            __syncthreads();

            // ---- MFMA: H branch (waves whose h-tile lives in this half) ----
            if ((v >> 2) == half) {
                const int hl = (v & 3)*16 + (l & 15);
                const int kb = l & 15;
                #pragma unroll
                for (int ws2 = 0; ws2 < 4; ++ws2) {
                    const int wb = ws2*32 + (l>>4)*8;
                    short8v A  = *(const short8v*)&t2lds[hl*128 + (wb ^ ((hl&7)<<3))];
                    short8v B  = *(const short8v*)&kH  [kb*128 + (wb ^ ((kb&7)<<3))];
                    accH = __builtin_amdgcn_mfma_f32_16x16x32_bf16(A, B, accH, 0, 0, 0);
                }
            }
            // ---- MFMA: W branch (all waves; wave v owns w-tile v) ----
            {
                const int kb = l & 15;
                const int w  = v*16 + (l & 15);
                #pragma unroll
                for (int hs = 0; hs < 2; ++hs) {
                    const int hloc = hs*32 + (l>>4)*8;
                    const int hg   = half*64 + hloc;
                    short8v A = *(const short8v*)&kWT[kb*128 + (hg  ^ ((kb&7)<<3))];
                    short8v B = *(const short8v*)&t2T[w*64   + (hloc ^ (((w>>1)&7)<<3))];
                    accW = __builtin_amdgcn_mfma_f32_16x16x32_bf16(A, B, accW, 0, 0, 0);
                }
            }
            __syncthreads();
        }
    }

    // ---------- write partials (accumulated over 4 c's) ----------
    {
        const size_t pb = ((size_t)(b*64 + grp)) * 2048;
        #pragma unroll
        for (int r = 0; r < 4; ++r) {
            const int h = v*16 + (l>>4)*4 + r;
            PH[pb + h*16 + (l&15)] = accH[r];
            const int k = (l>>4)*4 + r;
            PW[pb + k*128 + v*16 + (l&15)] = accW[r];
        }
    }
}

// ============ Kernel 2: reduce partials (64 grp-records) -> energy[8][4096] ====
__global__ __launch_bounds__(256) void energy_reduce(
    const float* __restrict__ PH, const float* __restrict__ PW,
    float* __restrict__ energy, float* __restrict__ bmin, float* __restrict__ bmax)
{
    const int bidx = blockIdx.x;           // 0..511
    const int tid  = threadIdx.x;
    const int ol   = tid & 63, qd = tid >> 6;
    const int o    = bidx*64 + ol;         // 0..32767
    __shared__ float red[4][64];

    const int isW = o >> 14;
    const int oo  = o & 16383;
    const int b   = oo >> 11, i = oo & 2047;
    const float* P = (isW ? PW : PH) + (size_t)b*64*2048 + i;
    float s = 0.f;
    #pragma unroll
    for (int j = 0; j < 16; ++j) s += P[(size_t)(qd*16 + j)*2048];
    red[qd][ol] = s;
    __syncthreads();

    if (tid < 64) {
        float v = red[0][tid] + red[1][tid] + red[2][tid] + red[3][tid];
        const int o2 = bidx*64 + tid;
        const int oo2 = o2 & 16383;
        const int b2 = oo2 >> 11, i2 = oo2 & 2047;
        const size_t dst = (o2 >> 14)
            ? ((size_t)b2*4096 + 2048 + (size_t)(i2 & 127)*16 + (i2 >> 7))
            : ((size_t)b2*4096 + i2);
        energy[dst] = v;
        float mn = v, mx = v;
        #pragma unroll
        for (int sft = 32; sft > 0; sft >>= 1) {
            mn = fminf(mn, __shfl_xor(mn, sft));
            mx = fmaxf(mx, __shfl_xor(mx, sft));
        }
        if (tid == 0) { bmin[bidx] = mn; bmax[bidx] = mx; }
    }
}

// ============ Kernel 3: recombination, softmax computed inline ============
// grid 2048 (b = bid&7, c = bid>>3), block 256 (4 waves).
__global__ __launch_bounds__(256) void out_kernel(
    const float* __restrict__ t2,
    const unsigned short* __restrict__ valHT,   // [b][c][w][16]
    const unsigned short* __restrict__ valWbf,  // [b][c][h][16]
    const float* __restrict__ energy,           // [b][4096]
    const float* __restrict__ bmin, const float* __restrict__ bmax,
    float* __restrict__ out)
{
    __shared__ __align__(16) unsigned short attbf[4096];  // [h][16] | [w][16]  8KB
    __shared__ float rmn[4], rmx[4], rsum[4], bc2[2];

    const int bid = blockIdx.x;
    const int b = bid & 7, c = bid >> 3;
    const int bc = b*CC + c;
    const int tid = threadIdx.x;
    const int l  = tid & 63;
    const int wv = tid >> 6;       // 0..3
    const int ln = l & 15;
    const int q4 = l >> 4;         // k-quadrant
    const size_t tb = (size_t)bc * HW;

    // ---- global min/max from bmin/bmax[512] ----
    {
        float mn = fminf(bmin[tid], bmin[tid + 256]);
        float mx = fmaxf(bmax[tid], bmax[tid + 256]);
        #pragma unroll
        for (int s = 32; s > 0; s >>= 1) {
            mn = fminf(mn, __shfl_xor(mn, s));
            mx = fmaxf(mx, __shfl_xor(mx, s));
        }
        if (l == 0) { rmn[wv] = mn; rmx[wv] = mx; }
    }
    __syncthreads();
    if (tid == 0) {
        float a = fminf(fminf(rmn[0], rmn[1]), fminf(rmn[2], rmn[3]));
        float m = fmaxf(fmaxf(rmx[0], rmx[1]), fmaxf(rmx[2], rmx[3]));
        bc2[0] = a; bc2[1] = 1.0f / (m - a);
    }
    __syncthreads();
    const float gmn = bc2[0];
    const float inv = bc2[1];

    // ---- softmax over the full 4096 (thread owns 16 contiguous values) ----
    float ex[16];
    {
        const float4* ep = (const float4*)(energy + (size_t)b*4096 + tid*16);
        float4 e0 = ep[0], e1 = ep[1], e2 = ep[2], e3 = ep[3];
        ex[0]=__expf((e0.x-gmn)*inv); ex[1]=__expf((e0.y-gmn)*inv);
        ex[2]=__expf((e0.z-gmn)*inv); ex[3]=__expf((e0.w-gmn)*inv);
        ex[4]=__expf((e1.x-gmn)*inv); ex[5]=__expf((e1.y-gmn)*inv);
        ex[6]=__expf((e1.z-gmn)*inv); ex[7]=__expf((e1.w-gmn)*inv);
        ex[8]=__expf((e2.x-gmn)*inv); ex[9]=__expf((e2.y-gmn)*inv);
        ex[10]=__expf((e2.z-gmn)*inv); ex[11]=__expf((e2.w-gmn)*inv);
        ex[12]=__expf((e3.x-gmn)*inv); ex[13]=__expf((e3.y-gmn)*inv);
        ex[14]=__expf((e3.z-gmn)*inv); ex[15]=__expf((e3.w-gmn)*inv);
        float ls = 0.f;
        #pragma unroll
        for (int i = 0; i < 16; ++i) ls += ex[i];
        #pragma unroll
        for (int s = 32; s > 0; s >>= 1) ls += __shfl_xor(ls, s);
        if (l == 0) rsum[wv] = ls;
    }
    __syncthreads();
    if (tid == 0) bc2[0] = 1.0f / (rsum[0] + rsum[1] + rsum[2] + rsum[3]);
    __syncthreads();
    {
        const float rinv = bc2[0];
        short8v o0, o1;
        #pragma unroll
        for (int i = 0; i < 8; ++i) o0[i] = f2bf(ex[i] * rinv);
        #pragma unroll
        for (int i = 0; i < 8; ++i) o1[i] = f2bf(ex[8 + i] * rinv);
        *(short8v*)&attbf[tid*16]     = o0;
        *(short8v*)&attbf[tid*16 + 8] = o1;
    }
    __syncthreads();

    // ---- MFMA epilogue (att from LDS; vals from global) ----
    const unsigned short* vHT = valHT  + (size_t)bc*2048;   // [w][16]
    const unsigned short* vW  = valWbf + (size_t)bc*2048;   // [h][16]

    short8v Bf[8];
    #pragma unroll
    for (int tw = 0; tw < 8; ++tw) {
        if (q4 < 2)
            Bf[tw] = *(const short8v*)&vHT[(tw*16 + ln)*16 + (q4 & 1)*8];
        else
            Bf[tw] = *(const short8v*)&attbf[2048 + (tw*16 + ln)*16 + (q4 & 1)*8];
    }

    #pragma unroll
    for (int t = 0; t < 2; ++t) {
        const int th = wv*2 + t;
        short8v Af;
        if (q4 < 2)
            Af = *(const short8v*)&attbf[(th*16 + ln)*16 + (q4 & 1)*8];
        else
            Af = *(const short8v*)&vW[(th*16 + ln)*16 + (q4 & 1)*8];
        #pragma unroll
        for (int tw = 0; tw < 8; ++tw) {
            float4v acc = {0.f,0.f,0.f,0.f};
            acc = __builtin_amdgcn_mfma_f32_16x16x32_bf16(Af, Bf[tw], acc, 0, 0, 0);
            const size_t base = tb + (size_t)(th*16 + q4*4)*128 + tw*16 + ln;
            #pragma unroll
            for (int r = 0; r < 4; ++r) {
                const float tv = t2[base + (size_t)r*128];
                out[base + (size_t)r*128] = fmaf(0.5f, acc[r], tv);
            }
        }
    }
}

extern "C" void kernel_launch(void* const* d_in, const int* in_sizes, int n_in,
                              void* d_out, int out_size, void* d_ws, size_t ws_size,
                              hipStream_t stream)
{
    const float* t1 = (const float*)d_in[0];
    const float* t2 = (const float*)d_in[1];
    float* out = (float*)d_out;
    char*  ws  = (char*)d_ws;

    unsigned short* valHT  = (unsigned short*)ws;                       // 8 MB
    unsigned short* valWbf = (unsigned short*)(ws + ((size_t)8 << 20)); // 8 MB
    float* energy = (float*)(ws + ((size_t)16 << 20));                  // 128 KB
    float* bmin   = energy + 32768;
    float* bmax   = bmin + 512;

    // partials live in d_out (8 MB of 134 MB), overwritten by out_kernel
    float* PH = out;                        // 512*2048 floats = 4 MB
    float* PW = out + (size_t)1048576;      // 4 MB

    hipLaunchKernelGGL(fused_pool_energy, dim3(512), dim3(512), 0, stream,
                       t1, t2, valHT, valWbf, PH, PW);
    hipLaunchKernelGGL(energy_reduce, dim3(512), dim3(256), 0, stream,
                       PH, PW, energy, bmin, bmax);
    hipLaunchKernelGGL(out_kernel, dim3(2048), dim3(256), 0, stream,
                       t2, valHT, valWbf, energy, bmin, bmax, out);
}